// Round 1
// baseline (1602.483 us; speedup 1.0000x reference)
//
#include <hip/hip_runtime.h>
#include <stdint.h>

#define BB 256
#define TT 128
#define DD 512
#define HH 512
#define G4 2048      // 4H
#define KT 1024      // D + H
#define BH (BB*HH)   // 131072

typedef short bf16x8 __attribute__((ext_vector_type(8)));
typedef float f32x4  __attribute__((ext_vector_type(4)));

__device__ __forceinline__ unsigned short f2bf(float f){
  union { float f; unsigned u; } v; v.f = f;
  unsigned u = v.u;
  unsigned r = (u + 0x7FFFu + ((u >> 16) & 1u)) >> 16;
  return (unsigned short)r;
}

// x [B,T,D] f32 -> xtr [T,B,D] bf16
__global__ void prep_x_k(const float* __restrict__ x, unsigned short* __restrict__ xtr){
  const int n4 = BB*TT*(DD/4);
  for (int i = blockIdx.x*blockDim.x + threadIdx.x; i < n4; i += gridDim.x*blockDim.x){
    int d4 = i & (DD/4 - 1);
    int b  = (i / (DD/4)) & (BB-1);
    int t  = i / ((DD/4)*BB);
    float4 v = *(const float4*)(x + (((size_t)b*TT + t)*DD + (size_t)d4*4));
    ushort4 o;
    o.x = f2bf(v.x); o.y = f2bf(v.y); o.z = f2bf(v.z); o.w = f2bf(v.w);
    *(ushort4*)(xtr + (((size_t)t*BB + b)*DD + (size_t)d4*4)) = o;
  }
}

// Wcat_t[dir][n'][k]: n' = hb*64 + g*16 + j  <->  orig col n = g*512 + hb*16 + j
// k<512 -> W[k][n], k>=512 -> U[k-512][n].  bf16.
__global__ void prep_w_k(const float* __restrict__ Wf, const float* __restrict__ Uf,
                         const float* __restrict__ Wb, const float* __restrict__ Ub,
                         unsigned short* __restrict__ wcat){
  const int tot = 2*G4*KT;  // 4M
  for (int i = blockIdx.x*blockDim.x + threadIdx.x; i < tot; i += gridDim.x*blockDim.x){
    int k   = i & (KT-1);
    int np  = (i >> 10) & (G4-1);
    int dir = i >> 21;
    int j  = np & 15;
    int g  = (np >> 4) & 3;
    int hb = np >> 6;
    int n  = g*HH + hb*16 + j;
    const float* W = dir ? Wb : Wf;
    const float* U = dir ? Ub : Uf;
    float v = (k < DD) ? W[(size_t)k*G4 + n] : U[(size_t)(k-DD)*G4 + n];
    wcat[i] = f2bf(v);
  }
}

__global__ void prep_bias_k(const float* __restrict__ bf_, const float* __restrict__ bb_,
                            float* __restrict__ bias_sw){
  int i = blockIdx.x*blockDim.x + threadIdx.x;
  if (i < 2*G4){
    int np  = i & (G4-1);
    int dir = i >> 11;
    int j = np & 15, g = (np>>4)&3, hb = np>>6;
    const float* src = dir ? bb_ : bf_;
    bias_sw[i] = src[g*HH + hb*16 + j];
  }
}

// One timestep, both directions. 256 blocks x 256 threads.
// block: dir = bid>>7, mb = (bid>>5)&3 (64 batch rows), hb = bid&31 (16 h cols x 4 gates)
__global__ __launch_bounds__(256, 2)
void lstm_step_k(const unsigned short* __restrict__ xtr,
                 const unsigned short* __restrict__ wcat,
                 const float* __restrict__ bias_sw,
                 float* __restrict__ cstate,
                 unsigned short* __restrict__ hbf,
                 float* __restrict__ out,
                 int s)
{
  __shared__ __align__(1024) unsigned short lds[2][8192];  // [buf][ A: 64x64 | B: 64x64 ] bf16
  const int tid  = threadIdx.x;
  const int lane = tid & 63;
  const int w    = tid >> 6;
  const int bid  = blockIdx.x;
  const int dir  = bid >> 7;
  const int mb   = (bid >> 5) & 3;
  const int hb   = bid & 31;
  const int t    = dir ? (TT-1-s) : s;
  const int m0   = mb * 64;
  const int n0   = hb * 64;

  const unsigned short* hin = hbf + (size_t)((s&1)*2 + dir)*BH;
  unsigned short* hout      = hbf + (size_t)(((s&1)^1)*2 + dir)*BH;
  const unsigned short* xt  = xtr + (size_t)t*BB*DD;
  const unsigned short* wb2 = wcat + (size_t)dir*G4*KT + (size_t)n0*KT;

  // stage K-chunk kc (64 wide) of A[64][64] and B[64][64] with XOR-swizzled source
  auto stage = [&](int kc, int bufi){
    const unsigned short* asrc = (kc < 8)
        ? (xt  + (size_t)m0*DD + (size_t)kc*64)
        : (hin + (size_t)m0*HH + (size_t)(kc-8)*64);
    const unsigned short* bsrc = wb2 + (size_t)kc*64;
    unsigned short* ab = &lds[bufi][0];
    unsigned short* bbuf = &lds[bufi][4096];
    #pragma unroll
    for (int inst = 0; inst < 2; ++inst){
      int u   = (w*2 + inst)*64 + lane;   // 16B unit index within 8KB tile
      int row = u >> 3, uu = u & 7;
      int su  = uu ^ (row & 7);           // pre-swizzled global source (m173 pattern)
      __builtin_amdgcn_global_load_lds(
        (const __attribute__((address_space(1))) void*)(asrc + (size_t)row*DD + su*8),
        (__attribute__((address_space(3))) void*)(ab + (w*2+inst)*512), 16, 0, 0);
      __builtin_amdgcn_global_load_lds(
        (const __attribute__((address_space(1))) void*)(bsrc + (size_t)row*KT + su*8),
        (__attribute__((address_space(3))) void*)(bbuf + (w*2+inst)*512), 16, 0, 0);
    }
  };

  f32x4 acc[4];
  #pragma unroll
  for (int f = 0; f < 4; ++f) acc[f] = (f32x4){0.f,0.f,0.f,0.f};

  stage(0, 0);
  __syncthreads();

  const int rowA = (w<<4) + (lane & 15);
  const int q    = lane >> 4;

  for (int kc = 0; kc < 16; ++kc){
    int cur = kc & 1;
    if (kc < 15) stage(kc+1, cur^1);
    const unsigned short* A  = &lds[cur][0];
    const unsigned short* Bm = &lds[cur][4096];
    #pragma unroll
    for (int kk = 0; kk < 2; ++kk){
      int un = kk*4 + q;                  // 16B unit along K
      bf16x8 a = *(const bf16x8*)(A + rowA*64 + ((un ^ (rowA & 7)) << 3));
      #pragma unroll
      for (int f = 0; f < 4; ++f){
        int rowB = (f<<4) + (lane & 15);
        bf16x8 bfr = *(const bf16x8*)(Bm + rowB*64 + ((un ^ (rowB & 7)) << 3));
        acc[f] = __builtin_amdgcn_mfma_f32_16x16x32_bf16(a, bfr, acc[f], 0, 0, 0);
      }
    }
    __syncthreads();
  }

  // epilogue: acc[gate][reg]; C/D layout: col = lane&15, row = (lane>>4)*4 + reg
  const float* biasd = bias_sw + dir*G4 + n0;
  const int jl = lane & 15;
  const int j  = (hb<<4) + jl;
  float bi0 = biasd[jl];
  float bi1 = biasd[16 + jl];
  float bi2 = biasd[32 + jl];
  float bi3 = biasd[48 + jl];
  #pragma unroll
  for (int rr = 0; rr < 4; ++rr){
    int brow = m0 + (w<<4) + (q<<2) + rr;
    size_t cix = ((size_t)dir*BB + brow)*HH + j;
    float zi = acc[0][rr] + bi0;
    float zf = acc[1][rr] + bi1;
    float zg = acc[2][rr] + bi2;
    float zo = acc[3][rr] + bi3;
    float ig = 1.0f/(1.0f + __expf(-zi));
    float fg = 1.0f/(1.0f + __expf(-zf));
    float gg = tanhf(zg);
    float og = 1.0f/(1.0f + __expf(-zo));
    float c  = fg*cstate[cix] + ig*gg;
    cstate[cix] = c;
    float h = og * tanhf(c);
    out[((size_t)brow*TT + t)*(2*HH) + (size_t)dir*HH + j] = h;
    hout[(size_t)brow*HH + j] = f2bf(h);
  }
}

// sent_emb[b][n] = word_emb[b][T-1][n] (n<H) or word_emb[b][0][n] (n>=H)
__global__ void final_k(float* __restrict__ out){
  int i = blockIdx.x*blockDim.x + threadIdx.x;
  if (i < BB*2*HH){
    int b = i >> 10;
    int n = i & 1023;
    int t = (n < HH) ? (TT-1) : 0;
    out[(size_t)BB*TT*2*HH + i] = out[((size_t)b*TT + t)*2*HH + n];
  }
}

extern "C" void kernel_launch(void* const* d_in, const int* in_sizes, int n_in,
                              void* d_out, int out_size, void* d_ws, size_t ws_size,
                              hipStream_t stream)
{
  const float* x   = (const float*)d_in[0];
  const float* Wf  = (const float*)d_in[1];
  const float* Uf  = (const float*)d_in[2];
  const float* bf_ = (const float*)d_in[3];
  const float* Wb  = (const float*)d_in[4];
  const float* Ub  = (const float*)d_in[5];
  const float* bb_ = (const float*)d_in[6];
  float* out = (float*)d_out;

  char* ws = (char*)d_ws;
  unsigned short* xtr  = (unsigned short*)ws;                                   // 33,554,432 B
  unsigned short* wcat = (unsigned short*)(ws + 33554432);                      //  8,388,608 B
  float* bias_sw       = (float*)(ws + 33554432 + 8388608);                     //     16,384 B
  float* cstate        = (float*)(ws + 33554432 + 8388608 + 16384);             //  1,048,576 B
  unsigned short* hbf  = (unsigned short*)(ws + 33554432 + 8388608 + 16384 + 1048576); // 1,048,576 B (2 parity x 2 dir x B*H bf16)

  hipMemsetAsync(cstate, 0, (size_t)2*BH*4, stream);
  hipMemsetAsync(hbf,    0, (size_t)2*BH*2, stream);   // parity-0 buffers (both dirs) = h0 = 0

  prep_x_k   <<<2048, 256, 0, stream>>>(x, xtr);
  prep_w_k   <<<4096, 256, 0, stream>>>(Wf, Uf, Wb, Ub, wcat);
  prep_bias_k<<<16,   256, 0, stream>>>(bf_, bb_, bias_sw);

  for (int s = 0; s < TT; ++s)
    lstm_step_k<<<256, 256, 0, stream>>>(xtr, wcat, bias_sw, cstate, hbf, out, s);

  final_k<<<1024, 256, 0, stream>>>(out);
}